// Round 2
// baseline (851.963 us; speedup 1.0000x reference)
//
#include <hip/hip_runtime.h>
#include <hip/hip_fp16.h>

#define BP_EPS 1e-12f
#define BP_K 8
#define LOG_C 2.0f      // centering offset: stored = log(m) + LOG_C
#define BSH 6           // nodes per bucket = 64
#define BNODES 64
#define NB1 512         // edge chunks (blocks) for hist + scatter

typedef __attribute__((ext_vector_type(8))) _Float16 half8;

// ===========================================================================
// Build: group directed edges by destination node WITHOUT global atomics.
// Payload encoding: at node u (=src) the incoming direction is (v->u) =
// (e<<1)|1 (msgs row e+Eu); at node v it's (u->v) = (e<<1)|0 (msgs row e).
// k_csr also emits pos[payload] = slot, and k_rev derives rev_slot[s] =
// slot of the reverse directed edge. Messages LIVE in CSR slot order, so
// aggregation is fully sequential and the update scatter-writes each new
// message to its destination slot (rev is a permutation -> no atomics).
// ===========================================================================

__global__ void k_hist(const int* __restrict__ src, const int* __restrict__ dst,
                       int* __restrict__ G, int Eu, int nbuck) {
    extern __shared__ int h[];
    for (int i = threadIdx.x; i < nbuck; i += blockDim.x) h[i] = 0;
    __syncthreads();
    int per = (Eu + NB1 - 1) / NB1;
    int s0 = blockIdx.x * per;
    int s1 = min(s0 + per, Eu);
    for (int e = s0 + threadIdx.x; e < s1; e += blockDim.x) {
        atomicAdd(&h[src[e] >> BSH], 1);
        atomicAdd(&h[dst[e] >> BSH], 1);
    }
    __syncthreads();
    for (int b = threadIdx.x; b < nbuck; b += blockDim.x)
        G[blockIdx.x * nbuck + b] = h[b];
}

__global__ void k_scanG(const int* __restrict__ G, int* __restrict__ Gpre,
                        int* __restrict__ total, int nbuck) {
    __shared__ int buf[NB1];
    int b = blockIdx.x;
    int t = threadIdx.x;
    int v = G[t * nbuck + b];
    buf[t] = v;
    __syncthreads();
    for (int off = 1; off < NB1; off <<= 1) {
        int x = (t >= off) ? buf[t - off] : 0;
        __syncthreads();
        buf[t] += x;
        __syncthreads();
    }
    Gpre[b * NB1 + t] = buf[t] - v;
    if (t == NB1 - 1) total[b] = buf[t];
}

__global__ void k_scanT(const int* __restrict__ total, int* __restrict__ base,
                        int nbuck, int* __restrict__ row_n, int E) {
    __shared__ int buf[1024];
    int t = threadIdx.x;
    int carry = 0;
    for (int s = 0; s < nbuck; s += 1024) {
        int i = s + t;
        int v = (i < nbuck) ? total[i] : 0;
        buf[t] = v;
        __syncthreads();
        for (int off = 1; off < 1024; off <<= 1) {
            int x = (t >= off) ? buf[t - off] : 0;
            __syncthreads();
            buf[t] += x;
            __syncthreads();
        }
        if (i < nbuck) base[i] = carry + buf[t] - v;
        carry += buf[1023];
        __syncthreads();
    }
    if (t == 0) { base[nbuck] = carry; *row_n = E; }
}

__global__ void k_scatter(const int* __restrict__ src, const int* __restrict__ dst,
                          const int* __restrict__ Gpre, const int* __restrict__ base,
                          int2* __restrict__ items, int Eu, int nbuck) {
    extern __shared__ int cur[];
    int blk = blockIdx.x;
    for (int i = threadIdx.x; i < nbuck; i += blockDim.x)
        cur[i] = base[i] + Gpre[i * NB1 + blk];
    __syncthreads();
    int per = (Eu + NB1 - 1) / NB1;
    int s0 = blk * per;
    int s1 = min(s0 + per, Eu);
    for (int e = s0 + threadIdx.x; e < s1; e += blockDim.x) {
        int u = src[e], v = dst[e];
        int pu = atomicAdd(&cur[u >> BSH], 1);
        items[pu] = make_int2(u, (e << 1) | 1);
        int pv = atomicAdd(&cur[v >> BSH], 1);
        items[pv] = make_int2(v, (e << 1) | 0);
    }
}

// bucket -> per-node CSR; also emit pos[payload] = slot for rev_slot build.
__global__ void k_csr(const int2* __restrict__ items, const int* __restrict__ base,
                      int* __restrict__ row, int* __restrict__ adj,
                      int* __restrict__ pos, int n) {
    __shared__ int deg[BNODES];
    __shared__ int cur[BNODES];
    int b = blockIdx.x;
    int lo = base[b], hi = base[b + 1];
    int node0 = b << BSH;
    if (threadIdx.x < BNODES) deg[threadIdx.x] = 0;
    __syncthreads();
    for (int i = lo + threadIdx.x; i < hi; i += blockDim.x)
        atomicAdd(&deg[items[i].x - node0], 1);
    __syncthreads();
    if (threadIdx.x == 0) {
        int acc = 0;
        for (int t = 0; t < BNODES; ++t) { int d = deg[t]; deg[t] = acc; acc += d; }
    }
    __syncthreads();
    if (threadIdx.x < BNODES) {
        int node = node0 + threadIdx.x;
        if (node < n) row[node] = lo + deg[threadIdx.x];
        cur[threadIdx.x] = deg[threadIdx.x];
    }
    __syncthreads();
    for (int i = lo + threadIdx.x; i < hi; i += blockDim.x) {
        int2 x = items[i];
        int p = atomicAdd(&cur[x.x - node0], 1);
        adj[lo + p] = x.y;
        pos[x.y] = lo + p;
    }
}

// rev_slot[s] = slot holding the reverse directed edge of slot s.
__global__ void k_rev(const int* __restrict__ adj, const int* __restrict__ pos,
                      int* __restrict__ rev, int E) {
    int s = blockIdx.x * blockDim.x + threadIdx.x;
    if (s < E) rev[s] = pos[adj[s] ^ 1];
}

// LP[i][k] = log(max(prior, eps)) -- folded into the aggregate S once.
__global__ void k_lp(const float* __restrict__ prior, float* __restrict__ LP, int n8) {
    int i = blockIdx.x * blockDim.x + threadIdx.x;
    if (i < n8) LP[i] = logf(fmaxf(prior[i], BP_EPS));
}

// ===========================================================================
// Fused iteration: half-wave (32 lanes) per node.
// pass 1: S[i] = sum of stored log-messages over row(i) (+ log prior) --
//         sequential W reads (FIRST: gather fp32 input msgs via adj).
// pass 2: per slot s=(j->i): m_new(i->j) = norm(max(exp(S-lm[s]),eps) @ psi),
//         scatter-write 16B to W_next[rev[s]]. rev is a permutation ->
//         every slot written exactly once, no atomics.
// ===========================================================================
template <bool FIRST>
__global__ void __launch_bounds__(256) k_it(
        const float* __restrict__ msgs, const _Float16* __restrict__ Wc,
        const int* __restrict__ row, const int* __restrict__ adj,
        const int* __restrict__ rev, const float* __restrict__ LP,
        const float* __restrict__ potential, _Float16* __restrict__ Wn,
        int Eu, int n) {
    __shared__ float psi[BP_K * BP_K];
    if (threadIdx.x < BP_K * BP_K) psi[threadIdx.x] = expf(potential[threadIdx.x]);
    __syncthreads();

    int half = threadIdx.x >> 5;
    int sl = threadIdx.x & 31;
    int i = blockIdx.x * 8 + half;
    if (i >= n) return;

    int r0 = row[i];
    int r1 = row[i + 1];

    float s[BP_K];
#pragma unroll
    for (int k = 0; k < BP_K; ++k) s[k] = 0.0f;

    for (int j = r0 + sl; j < r1; j += 32) {
        if (FIRST) {
            int a = adj[j];
            int id = (a >> 1) + (a & 1) * Eu;
            const float4* m4 = (const float4*)(msgs + (size_t)id * BP_K);
            float4 x = m4[0];
            float4 y = m4[1];
            float v[BP_K] = {x.x, x.y, x.z, x.w, y.x, y.y, y.z, y.w};
#pragma unroll
            for (int k = 0; k < BP_K; ++k) s[k] += logf(fmaxf(v[k], BP_EPS));
        } else {
            half8 h = *(const half8*)(Wc + (size_t)j * BP_K);
#pragma unroll
            for (int k = 0; k < BP_K; ++k) s[k] += (float)h[k] - LOG_C;
        }
    }

#pragma unroll
    for (int off = 16; off >= 1; off >>= 1) {
#pragma unroll
        for (int k = 0; k < BP_K; ++k) s[k] += __shfl_xor(s[k], off);
    }

    // fold in log prior (all 32 lanes need it for pass 2)
    {
        const float4* lp4 = (const float4*)(LP + (size_t)i * BP_K);
        float4 la = lp4[0], lb = lp4[1];
        s[0] += la.x; s[1] += la.y; s[2] += la.z; s[3] += la.w;
        s[4] += lb.x; s[5] += lb.y; s[6] += lb.z; s[7] += lb.w;
    }

    // pass 2: emit outgoing messages (reverse slots), reads hit L1/L2.
    for (int j = r0 + sl; j < r1; j += 32) {
        float lm[BP_K];
        if (FIRST) {
            int a = adj[j];
            int id = (a >> 1) + (a & 1) * Eu;
            const float4* m4 = (const float4*)(msgs + (size_t)id * BP_K);
            float4 x = m4[0];
            float4 y = m4[1];
            float v[BP_K] = {x.x, x.y, x.z, x.w, y.x, y.y, y.z, y.w};
#pragma unroll
            for (int k = 0; k < BP_K; ++k) lm[k] = logf(fmaxf(v[k], BP_EPS));
        } else {
            half8 h = *(const half8*)(Wc + (size_t)j * BP_K);
#pragma unroll
            for (int k = 0; k < BP_K; ++k) lm[k] = (float)h[k] - LOG_C;
        }

        float bb[BP_K];
#pragma unroll
        for (int k = 0; k < BP_K; ++k)
            bb[k] = fmaxf(expf(s[k] - lm[k]), BP_EPS);

        float mn[BP_K];
        float sum = 0.0f;
#pragma unroll
        for (int jj = 0; jj < BP_K; ++jj) {
            float acc = 0.0f;
#pragma unroll
            for (int k = 0; k < BP_K; ++k) acc += bb[k] * psi[k * BP_K + jj];
            mn[jj] = acc;
            sum += acc;
        }
        float inv = 1.0f / fmaxf(sum, BP_EPS);

        half8 o;
#pragma unroll
        for (int jj = 0; jj < BP_K; ++jj)
            o[jj] = (_Float16)(logf(fmaxf(mn[jj] * inv, BP_EPS)) + LOG_C);

        *(half8*)(Wn + (size_t)rev[j] * BP_K) = o;
    }
}

// Final beliefs: sequential row read, normalize with prior (via LP).
__global__ void __launch_bounds__(256) k_belief(
        const _Float16* __restrict__ Wc, const int* __restrict__ row,
        const float* __restrict__ LP, float* __restrict__ out, int n) {
    int half = threadIdx.x >> 5;
    int sl = threadIdx.x & 31;
    int i = blockIdx.x * 8 + half;
    if (i >= n) return;

    int r0 = row[i];
    int r1 = row[i + 1];

    float s[BP_K];
#pragma unroll
    for (int k = 0; k < BP_K; ++k) s[k] = 0.0f;

    for (int j = r0 + sl; j < r1; j += 32) {
        half8 h = *(const half8*)(Wc + (size_t)j * BP_K);
#pragma unroll
        for (int k = 0; k < BP_K; ++k) s[k] += (float)h[k] - LOG_C;
    }

#pragma unroll
    for (int off = 16; off >= 1; off >>= 1) {
#pragma unroll
        for (int k = 0; k < BP_K; ++k) s[k] += __shfl_xor(s[k], off);
    }

    if (sl == 0) {
        const float4* lp4 = (const float4*)(LP + (size_t)i * BP_K);
        float4 la = lp4[0], lb = lp4[1];
        float lp[BP_K] = {la.x, la.y, la.z, la.w, lb.x, lb.y, lb.z, lb.w};
        float b[BP_K];
        float sum = 0.0f;
#pragma unroll
        for (int k = 0; k < BP_K; ++k) {
            b[k] = fmaxf(expf(s[k] + lp[k]), BP_EPS);
            sum += b[k];
        }
        float inv = 1.0f / fmaxf(sum, BP_EPS);
        float4* o4 = (float4*)(out + (size_t)i * BP_K);
        o4[0] = {b[0] * inv, b[1] * inv, b[2] * inv, b[3] * inv};
        o4[1] = {b[4] * inv, b[5] * inv, b[6] * inv, b[7] * inv};
    }
}

extern "C" void kernel_launch(void* const* d_in, const int* in_sizes, int n_in,
                              void* d_out, int out_size, void* d_ws, size_t ws_size,
                              hipStream_t stream) {
    const float* prior     = (const float*)d_in[0];
    const float* msgs      = (const float*)d_in[1];
    const float* potential = (const float*)d_in[2];
    const int*   src       = (const int*)d_in[3];
    const int*   dst       = (const int*)d_in[4];
    const int ITERS = 5;   // fixed by setup_inputs; rev is e+-Eu by construction

    int n  = in_sizes[0] / BP_K;
    int E  = in_sizes[3];
    int Eu = E / 2;
    int nbuck = (n + BNODES - 1) >> BSH;

    char* w = (char*)d_ws;
    _Float16* W1 = (_Float16*)w;   w += (size_t)Eu * 16 * sizeof(_Float16);
    _Float16* W2 = (_Float16*)w;   w += (size_t)Eu * 16 * sizeof(_Float16);
    int*   adj   = (int*)w;        w += (size_t)E * sizeof(int);
    float* LP    = (float*)w;      w += (size_t)n * BP_K * sizeof(float);
    int*   G     = (int*)w;        w += (size_t)NB1 * nbuck * sizeof(int);
    int*   Gpre  = (int*)w;        w += (size_t)NB1 * nbuck * sizeof(int);
    int*   total = (int*)w;        w += (size_t)nbuck * sizeof(int);
    int*   base  = (int*)w;        w += (size_t)(nbuck + 1) * sizeof(int);
    int*   row   = (int*)w;        w += (size_t)(n + 1) * sizeof(int);
    int*   rev   = (int*)w;        w += (size_t)E * sizeof(int);
    // items + pos alias W2: both dead before W2's first write (iteration 2).
    int2*  items = (int2*)W2;
    int*   pos   = (int*)((char*)W2 + (size_t)E * sizeof(int2));

    float* out = (float*)d_out;

    dim3 blk(256);
    dim3 grdE((E + 255) / 256);
    dim3 grdNode((n + 7) / 8);     // 8 half-waves/block, half-wave per node
    size_t lds_hist = (size_t)nbuck * sizeof(int);

    // --- build: bucket-grouping CSR + reverse-slot map, no global atomics ---
    k_hist   <<<NB1, blk, lds_hist, stream>>>(src, dst, G, Eu, nbuck);
    k_scanG  <<<nbuck, NB1, 0, stream>>>(G, Gpre, total, nbuck);
    k_scanT  <<<1, 1024, 0, stream>>>(total, base, nbuck, row + n, E);
    k_scatter<<<NB1, blk, lds_hist, stream>>>(src, dst, Gpre, base, items, Eu, nbuck);
    k_csr    <<<nbuck, blk, 0, stream>>>(items, base, row, adj, pos, n);
    k_rev    <<<grdE, blk, 0, stream>>>(adj, pos, rev, E);
    k_lp     <<<(n * BP_K + 255) / 256, blk, 0, stream>>>(prior, LP, n * BP_K);

    // --- iteration 1: gather fp32 input msgs (bit-identical math to before) ---
    k_it<true><<<grdNode, blk, 0, stream>>>(msgs, nullptr, row, adj, rev, LP,
                                            potential, W1, Eu, n);

    // --- iterations 2..5: fully fused, sequential read + scatter write ---
    _Float16* cur = W1;
    _Float16* nxt = W2;
    for (int it = 1; it < ITERS; ++it) {
        k_it<false><<<grdNode, blk, 0, stream>>>(nullptr, cur, row, nullptr, rev,
                                                 LP, potential, nxt, Eu, n);
        _Float16* tmp = cur; cur = nxt; nxt = tmp;
    }

    // --- final beliefs: sequential read of W, no adjacency needed ---
    k_belief<<<grdNode, blk, 0, stream>>>(cur, row, LP, out, n);
}

// Round 3
// 770.079 us; speedup vs baseline: 1.1063x; 1.1063x over previous
//
#include <hip/hip_runtime.h>
#include <hip/hip_fp16.h>

#define BP_EPS 1e-12f
#define BP_K 8
#define LOG_C 2.0f      // centering offset: stored = log(m) + LOG_C
#define BSH 6           // nodes per bucket = 64
#define BNODES 64
#define NB1 512         // edge chunks (blocks) for hist + scatter

typedef __attribute__((ext_vector_type(8))) _Float16 half8;

// ===========================================================================
// Build: group directed edges by destination node WITHOUT global atomics.
// Payload encoding: at node u (=src) the incoming direction is (v->u) =
// (e<<1)|1 (msgs row e+Eu); at node v it's (u->v) = (e<<1)|0 (msgs row e).
// k_csr also emits pos[payload] = slot; k_rev derives rev_slot[s] = slot of
// the reverse directed edge. Messages LIVE in CSR slot order: aggregation is
// fully sequential; the update scatter-writes to rev[s] (a permutation).
// ===========================================================================

__global__ void k_hist(const int* __restrict__ src, const int* __restrict__ dst,
                       int* __restrict__ G, int Eu, int nbuck) {
    extern __shared__ int h[];
    for (int i = threadIdx.x; i < nbuck; i += blockDim.x) h[i] = 0;
    __syncthreads();
    int per = (Eu + NB1 - 1) / NB1;
    int s0 = blockIdx.x * per;
    int s1 = min(s0 + per, Eu);
    for (int e = s0 + threadIdx.x; e < s1; e += blockDim.x) {
        atomicAdd(&h[src[e] >> BSH], 1);
        atomicAdd(&h[dst[e] >> BSH], 1);
    }
    __syncthreads();
    for (int b = threadIdx.x; b < nbuck; b += blockDim.x)
        G[blockIdx.x * nbuck + b] = h[b];
}

__global__ void k_scanG(const int* __restrict__ G, int* __restrict__ Gpre,
                        int* __restrict__ total, int nbuck) {
    __shared__ int buf[NB1];
    int b = blockIdx.x;
    int t = threadIdx.x;
    int v = G[t * nbuck + b];
    buf[t] = v;
    __syncthreads();
    for (int off = 1; off < NB1; off <<= 1) {
        int x = (t >= off) ? buf[t - off] : 0;
        __syncthreads();
        buf[t] += x;
        __syncthreads();
    }
    Gpre[b * NB1 + t] = buf[t] - v;
    if (t == NB1 - 1) total[b] = buf[t];
}

__global__ void k_scanT(const int* __restrict__ total, int* __restrict__ base,
                        int nbuck, int* __restrict__ row_n, int E) {
    __shared__ int buf[1024];
    int t = threadIdx.x;
    int carry = 0;
    for (int s = 0; s < nbuck; s += 1024) {
        int i = s + t;
        int v = (i < nbuck) ? total[i] : 0;
        buf[t] = v;
        __syncthreads();
        for (int off = 1; off < 1024; off <<= 1) {
            int x = (t >= off) ? buf[t - off] : 0;
            __syncthreads();
            buf[t] += x;
            __syncthreads();
        }
        if (i < nbuck) base[i] = carry + buf[t] - v;
        carry += buf[1023];
        __syncthreads();
    }
    if (t == 0) { base[nbuck] = carry; *row_n = E; }
}

__global__ void k_scatter(const int* __restrict__ src, const int* __restrict__ dst,
                          const int* __restrict__ Gpre, const int* __restrict__ base,
                          int2* __restrict__ items, int Eu, int nbuck) {
    extern __shared__ int cur[];
    int blk = blockIdx.x;
    for (int i = threadIdx.x; i < nbuck; i += blockDim.x)
        cur[i] = base[i] + Gpre[i * NB1 + blk];
    __syncthreads();
    int per = (Eu + NB1 - 1) / NB1;
    int s0 = blk * per;
    int s1 = min(s0 + per, Eu);
    for (int e = s0 + threadIdx.x; e < s1; e += blockDim.x) {
        int u = src[e], v = dst[e];
        int pu = atomicAdd(&cur[u >> BSH], 1);
        items[pu] = make_int2(u, (e << 1) | 1);
        int pv = atomicAdd(&cur[v >> BSH], 1);
        items[pv] = make_int2(v, (e << 1) | 0);
    }
}

// bucket -> per-node CSR; also emit pos[payload] = slot for rev_slot build.
__global__ void k_csr(const int2* __restrict__ items, const int* __restrict__ base,
                      int* __restrict__ row, int* __restrict__ adj,
                      int* __restrict__ pos, int n) {
    __shared__ int deg[BNODES];
    __shared__ int cur[BNODES];
    int b = blockIdx.x;
    int lo = base[b], hi = base[b + 1];
    int node0 = b << BSH;
    if (threadIdx.x < BNODES) deg[threadIdx.x] = 0;
    __syncthreads();
    for (int i = lo + threadIdx.x; i < hi; i += blockDim.x)
        atomicAdd(&deg[items[i].x - node0], 1);
    __syncthreads();
    if (threadIdx.x == 0) {
        int acc = 0;
        for (int t = 0; t < BNODES; ++t) { int d = deg[t]; deg[t] = acc; acc += d; }
    }
    __syncthreads();
    if (threadIdx.x < BNODES) {
        int node = node0 + threadIdx.x;
        if (node < n) row[node] = lo + deg[threadIdx.x];
        cur[threadIdx.x] = deg[threadIdx.x];
    }
    __syncthreads();
    for (int i = lo + threadIdx.x; i < hi; i += blockDim.x) {
        int2 x = items[i];
        int p = atomicAdd(&cur[x.x - node0], 1);
        adj[lo + p] = x.y;
        pos[x.y] = lo + p;
    }
}

// rev_slot[s] = slot holding the reverse directed edge of slot s.
__global__ void k_rev(const int* __restrict__ adj, const int* __restrict__ pos,
                      int* __restrict__ rev, int E) {
    int s = blockIdx.x * blockDim.x + threadIdx.x;
    if (s < E) rev[s] = pos[adj[s] ^ 1];
}

// LP[i][k] = log(max(prior, eps)) -- folded into the aggregate S once.
__global__ void k_lp(const float* __restrict__ prior, float* __restrict__ LP, int n8) {
    int i = blockIdx.x * blockDim.x + threadIdx.x;
    if (i < n8) LP[i] = __logf(fmaxf(prior[i], BP_EPS));
}

// ===========================================================================
// Fused iteration: half-wave (32 lanes) per node, SINGLE read pass.
// Each lane loads the log-message(s) for its slot(s) ONCE, keeping trips 0/1
// in registers (covers deg <= 64; rare longer rows reload). After the
// shuffle-reduce produces S[i] (+log prior), each lane emits the outgoing
// message for its cached slot(s): scatter-write 16B to W_next[rev[s]].
// rev is a permutation -> every slot written exactly once, no atomics.
// ===========================================================================
template <bool FIRST>
__global__ void __launch_bounds__(256) k_it(
        const float* __restrict__ msgs, const _Float16* __restrict__ Wc,
        const int* __restrict__ row, const int* __restrict__ adj,
        const int* __restrict__ rev, const float* __restrict__ LP,
        const float* __restrict__ potential, _Float16* __restrict__ Wn,
        int Eu, int n) {
    __shared__ float psi[BP_K * BP_K];
    if (threadIdx.x < BP_K * BP_K) psi[threadIdx.x] = expf(potential[threadIdx.x]);
    __syncthreads();

    int half = threadIdx.x >> 5;
    int sl = threadIdx.x & 31;
    int i = blockIdx.x * 8 + half;
    if (i >= n) return;

    int r0 = row[i];
    int r1 = row[i + 1];
    int j0 = r0 + sl;
    int j1 = j0 + 32;
    bool h0 = j0 < r1;
    bool h1 = j1 < r1;

    float s[BP_K];
#pragma unroll
    for (int k = 0; k < BP_K; ++k) s[k] = 0.0f;

    float lm0[BP_K], lm1[BP_K];
    int rv0 = 0, rv1 = 0;

    // ---- load trip 0 / trip 1 into registers, accumulate ----
    if (h0) {
        rv0 = rev[j0];
        if (FIRST) {
            int a = adj[j0];
            int id = (a >> 1) + (a & 1) * Eu;
            const float4* m4 = (const float4*)(msgs + (size_t)id * BP_K);
            float4 x = m4[0], y = m4[1];
            float v[BP_K] = {x.x, x.y, x.z, x.w, y.x, y.y, y.z, y.w};
#pragma unroll
            for (int k = 0; k < BP_K; ++k) lm0[k] = __logf(fmaxf(v[k], BP_EPS));
        } else {
            half8 h = *(const half8*)(Wc + (size_t)j0 * BP_K);
#pragma unroll
            for (int k = 0; k < BP_K; ++k) lm0[k] = (float)h[k] - LOG_C;
        }
#pragma unroll
        for (int k = 0; k < BP_K; ++k) s[k] += lm0[k];
    }
    if (h1) {
        rv1 = rev[j1];
        if (FIRST) {
            int a = adj[j1];
            int id = (a >> 1) + (a & 1) * Eu;
            const float4* m4 = (const float4*)(msgs + (size_t)id * BP_K);
            float4 x = m4[0], y = m4[1];
            float v[BP_K] = {x.x, x.y, x.z, x.w, y.x, y.y, y.z, y.w};
#pragma unroll
            for (int k = 0; k < BP_K; ++k) lm1[k] = __logf(fmaxf(v[k], BP_EPS));
        } else {
            half8 h = *(const half8*)(Wc + (size_t)j1 * BP_K);
#pragma unroll
            for (int k = 0; k < BP_K; ++k) lm1[k] = (float)h[k] - LOG_C;
        }
#pragma unroll
        for (int k = 0; k < BP_K; ++k) s[k] += lm1[k];
    }
    // rare: rows longer than 64
    for (int j = j0 + 64; j < r1; j += 32) {
        float t[BP_K];
        if (FIRST) {
            int a = adj[j];
            int id = (a >> 1) + (a & 1) * Eu;
            const float4* m4 = (const float4*)(msgs + (size_t)id * BP_K);
            float4 x = m4[0], y = m4[1];
            float v[BP_K] = {x.x, x.y, x.z, x.w, y.x, y.y, y.z, y.w};
#pragma unroll
            for (int k = 0; k < BP_K; ++k) t[k] = __logf(fmaxf(v[k], BP_EPS));
        } else {
            half8 h = *(const half8*)(Wc + (size_t)j * BP_K);
#pragma unroll
            for (int k = 0; k < BP_K; ++k) t[k] = (float)h[k] - LOG_C;
        }
#pragma unroll
        for (int k = 0; k < BP_K; ++k) s[k] += t[k];
    }

    // ---- reduce across the 32-lane half-wave ----
#pragma unroll
    for (int off = 16; off >= 1; off >>= 1) {
#pragma unroll
        for (int k = 0; k < BP_K; ++k) s[k] += __shfl_xor(s[k], off);
    }

    // fold in log prior (all lanes need it for the emit phase)
    {
        const float4* lp4 = (const float4*)(LP + (size_t)i * BP_K);
        float4 la = lp4[0], lb = lp4[1];
        s[0] += la.x; s[1] += la.y; s[2] += la.z; s[3] += la.w;
        s[4] += lb.x; s[5] += lb.y; s[6] += lb.z; s[7] += lb.w;
    }

    // ---- emit outgoing messages from cached registers ----
#define EMIT(LM, RV)                                                          \
    {                                                                         \
        float bb[BP_K];                                                       \
        _Pragma("unroll")                                                     \
        for (int k = 0; k < BP_K; ++k)                                        \
            bb[k] = fmaxf(__expf(s[k] - LM[k]), BP_EPS);                      \
        float mn[BP_K];                                                       \
        float sum = 0.0f;                                                     \
        _Pragma("unroll")                                                     \
        for (int jj = 0; jj < BP_K; ++jj) {                                   \
            float acc = 0.0f;                                                 \
            _Pragma("unroll")                                                 \
            for (int k = 0; k < BP_K; ++k) acc += bb[k] * psi[k * BP_K + jj]; \
            mn[jj] = acc;                                                     \
            sum += acc;                                                       \
        }                                                                     \
        float inv = 1.0f / fmaxf(sum, BP_EPS);                                \
        half8 o;                                                              \
        _Pragma("unroll")                                                     \
        for (int jj = 0; jj < BP_K; ++jj)                                     \
            o[jj] = (_Float16)(__logf(fmaxf(mn[jj] * inv, BP_EPS)) + LOG_C);  \
        *(half8*)(Wn + (size_t)(RV) * BP_K) = o;                              \
    }

    if (h0) EMIT(lm0, rv0);
    if (h1) EMIT(lm1, rv1);
    for (int j = j0 + 64; j < r1; j += 32) {
        float t[BP_K];
        if (FIRST) {
            int a = adj[j];
            int id = (a >> 1) + (a & 1) * Eu;
            const float4* m4 = (const float4*)(msgs + (size_t)id * BP_K);
            float4 x = m4[0], y = m4[1];
            float v[BP_K] = {x.x, x.y, x.z, x.w, y.x, y.y, y.z, y.w};
#pragma unroll
            for (int k = 0; k < BP_K; ++k) t[k] = __logf(fmaxf(v[k], BP_EPS));
        } else {
            half8 h = *(const half8*)(Wc + (size_t)j * BP_K);
#pragma unroll
            for (int k = 0; k < BP_K; ++k) t[k] = (float)h[k] - LOG_C;
        }
        int rv = rev[j];
        EMIT(t, rv);
    }
#undef EMIT
}

// Final beliefs: sequential row read, normalize with prior (via LP).
__global__ void __launch_bounds__(256) k_belief(
        const _Float16* __restrict__ Wc, const int* __restrict__ row,
        const float* __restrict__ LP, float* __restrict__ out, int n) {
    int half = threadIdx.x >> 5;
    int sl = threadIdx.x & 31;
    int i = blockIdx.x * 8 + half;
    if (i >= n) return;

    int r0 = row[i];
    int r1 = row[i + 1];

    float s[BP_K];
#pragma unroll
    for (int k = 0; k < BP_K; ++k) s[k] = 0.0f;

    for (int j = r0 + sl; j < r1; j += 32) {
        half8 h = *(const half8*)(Wc + (size_t)j * BP_K);
#pragma unroll
        for (int k = 0; k < BP_K; ++k) s[k] += (float)h[k] - LOG_C;
    }

#pragma unroll
    for (int off = 16; off >= 1; off >>= 1) {
#pragma unroll
        for (int k = 0; k < BP_K; ++k) s[k] += __shfl_xor(s[k], off);
    }

    if (sl == 0) {
        const float4* lp4 = (const float4*)(LP + (size_t)i * BP_K);
        float4 la = lp4[0], lb = lp4[1];
        float lp[BP_K] = {la.x, la.y, la.z, la.w, lb.x, lb.y, lb.z, lb.w};
        float b[BP_K];
        float sum = 0.0f;
#pragma unroll
        for (int k = 0; k < BP_K; ++k) {
            b[k] = fmaxf(__expf(s[k] + lp[k]), BP_EPS);
            sum += b[k];
        }
        float inv = 1.0f / fmaxf(sum, BP_EPS);
        float4* o4 = (float4*)(out + (size_t)i * BP_K);
        o4[0] = {b[0] * inv, b[1] * inv, b[2] * inv, b[3] * inv};
        o4[1] = {b[4] * inv, b[5] * inv, b[6] * inv, b[7] * inv};
    }
}

extern "C" void kernel_launch(void* const* d_in, const int* in_sizes, int n_in,
                              void* d_out, int out_size, void* d_ws, size_t ws_size,
                              hipStream_t stream) {
    const float* prior     = (const float*)d_in[0];
    const float* msgs      = (const float*)d_in[1];
    const float* potential = (const float*)d_in[2];
    const int*   src       = (const int*)d_in[3];
    const int*   dst       = (const int*)d_in[4];
    const int ITERS = 5;   // fixed by setup_inputs; rev is e+-Eu by construction

    int n  = in_sizes[0] / BP_K;
    int E  = in_sizes[3];
    int Eu = E / 2;
    int nbuck = (n + BNODES - 1) >> BSH;

    char* w = (char*)d_ws;
    _Float16* W1 = (_Float16*)w;   w += (size_t)Eu * 16 * sizeof(_Float16);
    _Float16* W2 = (_Float16*)w;   w += (size_t)Eu * 16 * sizeof(_Float16);
    int*   adj   = (int*)w;        w += (size_t)E * sizeof(int);
    float* LP    = (float*)w;      w += (size_t)n * BP_K * sizeof(float);
    int*   G     = (int*)w;        w += (size_t)NB1 * nbuck * sizeof(int);
    int*   Gpre  = (int*)w;        w += (size_t)NB1 * nbuck * sizeof(int);
    int*   total = (int*)w;        w += (size_t)nbuck * sizeof(int);
    int*   base  = (int*)w;        w += (size_t)(nbuck + 1) * sizeof(int);
    int*   row   = (int*)w;        w += (size_t)(n + 1) * sizeof(int);
    int*   rev   = (int*)w;        w += (size_t)E * sizeof(int);
    // items + pos alias W2: both dead before W2's first write (iteration 2).
    int2*  items = (int2*)W2;
    int*   pos   = (int*)((char*)W2 + (size_t)E * sizeof(int2));

    float* out = (float*)d_out;

    dim3 blk(256);
    dim3 grdE((E + 255) / 256);
    dim3 grdNode((n + 7) / 8);     // 8 half-waves/block, half-wave per node
    size_t lds_hist = (size_t)nbuck * sizeof(int);

    // --- build: bucket-grouping CSR + reverse-slot map, no global atomics ---
    k_hist   <<<NB1, blk, lds_hist, stream>>>(src, dst, G, Eu, nbuck);
    k_scanG  <<<nbuck, NB1, 0, stream>>>(G, Gpre, total, nbuck);
    k_scanT  <<<1, 1024, 0, stream>>>(total, base, nbuck, row + n, E);
    k_scatter<<<NB1, blk, lds_hist, stream>>>(src, dst, Gpre, base, items, Eu, nbuck);
    k_csr    <<<nbuck, blk, 0, stream>>>(items, base, row, adj, pos, n);
    k_rev    <<<grdE, blk, 0, stream>>>(adj, pos, rev, E);
    k_lp     <<<(n * BP_K + 255) / 256, blk, 0, stream>>>(prior, LP, n * BP_K);

    // --- iteration 1: gather fp32 input msgs ONCE (register-cached) ---
    k_it<true><<<grdNode, blk, 0, stream>>>(msgs, nullptr, row, adj, rev, LP,
                                            potential, W1, Eu, n);

    // --- iterations 2..5: sequential read (once) + scatter write ---
    _Float16* cur = W1;
    _Float16* nxt = W2;
    for (int it = 1; it < ITERS; ++it) {
        k_it<false><<<grdNode, blk, 0, stream>>>(nullptr, cur, row, nullptr, rev,
                                                 LP, potential, nxt, Eu, n);
        _Float16* tmp = cur; cur = nxt; nxt = tmp;
    }

    // --- final beliefs: sequential read of W, no adjacency needed ---
    k_belief<<<grdNode, blk, 0, stream>>>(cur, row, LP, out, n);
}